// Round 4
// baseline (182.482 us; speedup 1.0000x reference)
//
#include <hip/hip_runtime.h>

// x_final[k] = mean(replicates[k,:]) * (1 - 0.8^100)  — closed form of the
// 100-step SGD contraction x <- 0.8 x + 0.2 mean. One fused row-mean kernel:
// each block computes a partial sum over its row segment, pre-scales, and
// atomicAdd's into out[row] (d_out zeroed by a memset node). 128 MB read,
// HBM roofline ~20 us; measured total is dominated by harness reset traffic.

#define ROWS 64
#define COLS 500000
#define VEC4 (COLS / 4)            // 125000 float4 per row (row base 16B-aligned)
#define SEGS 32                    // blocks per row; grid = 2048 = 8 blocks/CU
#define THREADS 256
#define STRIDE (SEGS * THREADS)    // 8192 float4 grid stride within a row

__global__ __launch_bounds__(THREADS)
void row_mean_sgd(const float* __restrict__ in, float* __restrict__ out) {
    const int row = blockIdx.x >> 5;          // /SEGS
    const int seg = blockIdx.x & (SEGS - 1);
    const float4* __restrict__ rp =
        reinterpret_cast<const float4*>(in + (size_t)row * COLS);

    // 4 independent accumulators -> 4 loads in flight per thread
    double a0 = 0.0, a1 = 0.0, a2 = 0.0, a3 = 0.0;
    int i = seg * THREADS + threadIdx.x;
    for (; i + 3 * STRIDE < VEC4; i += 4 * STRIDE) {
        float4 v0 = rp[i];
        float4 v1 = rp[i + STRIDE];
        float4 v2 = rp[i + 2 * STRIDE];
        float4 v3 = rp[i + 3 * STRIDE];
        a0 += (double)v0.x + (double)v0.y + (double)v0.z + (double)v0.w;
        a1 += (double)v1.x + (double)v1.y + (double)v1.z + (double)v1.w;
        a2 += (double)v2.x + (double)v2.y + (double)v2.z + (double)v2.w;
        a3 += (double)v3.x + (double)v3.y + (double)v3.z + (double)v3.w;
    }
    for (; i < VEC4; i += STRIDE) {
        float4 v = rp[i];
        a0 += (double)v.x + (double)v.y + (double)v.z + (double)v.w;
    }
    double acc = (a0 + a1) + (a2 + a3);

    // wave-64 down-reduce
    #pragma unroll
    for (int off = 32; off > 0; off >>= 1)
        acc += __shfl_down(acc, off, 64);

    __shared__ double wsum[THREADS / 64];
    if ((threadIdx.x & 63) == 0) wsum[threadIdx.x >> 6] = acc;
    __syncthreads();
    if (threadIdx.x == 0) {
        double s = (wsum[0] + wsum[1]) + (wsum[2] + wsum[3]);
        // 0.8^100 = (0.8^10)^10, 0.8^10 = 0.1073741824 exact
        const double FACTOR = (1.0 - 2.0370359763344314e-10) / (double)COLS;
        atomicAdd(out + row, (float)(s * FACTOR));   // device-scope by default
    }
}

extern "C" void kernel_launch(void* const* d_in, const int* in_sizes, int n_in,
                              void* d_out, int out_size, void* d_ws, size_t ws_size,
                              hipStream_t stream) {
    const float* in = (const float*)d_in[0];
    float* out = (float*)d_out;

    hipMemsetAsync(out, 0, (size_t)out_size * sizeof(float), stream);
    hipLaunchKernelGGL(row_mean_sgd, dim3(ROWS * SEGS), dim3(THREADS), 0, stream,
                       in, out);
}